// Round 10
// baseline (706.228 us; speedup 1.0000x reference)
//
#include <hip/hip_runtime.h>
#include <math.h>

typedef unsigned int   uint;
typedef unsigned short ushort;

#define N_NODES 50000
#define DIM     128
#define N_EDGES 800000
#define N_UID   4096
#define LN_EPS  1e-5f
#define RST     132   // padded LDS row stride (floats)
#define NBUCK   196   // ceil(50000/256) buckets of 256 nodes

typedef __attribute__((ext_vector_type(8))) short bf16x8;
typedef __attribute__((ext_vector_type(4))) float f32x4;
typedef __attribute__((ext_vector_type(4))) uint  u32x4;

// ---- bf16 helpers (storage only; math fp32) ----
__device__ __forceinline__ float bf_lo(uint u) { return __builtin_bit_cast(float, u << 16); }
__device__ __forceinline__ float bf_hi(uint u) { return __builtin_bit_cast(float, u & 0xffff0000u); }
__device__ __forceinline__ uint pack_bf16(float a, float b) {   // RNE
    uint ua = __builtin_bit_cast(uint, a);
    uint ub = __builtin_bit_cast(uint, b);
    uint ra = (ua + 0x7fffu + ((ua >> 16) & 1u)) >> 16;
    uint rb = (ub + 0x7fffu + ((ub >> 16) & 1u)) >> 16;
    return ra | (rb << 16);
}

// ---------- prep: W -> bf16, zero bucket histogram ----------
__global__ __launch_bounds__(256) void prep_kernel(const float* __restrict__ W, ushort* __restrict__ WB,
                                                   int* __restrict__ bhist) {
    int i = blockIdx.x * 256 + threadIdx.x;
    if (i < 3 * DIM * DIM / 4) {
        const float4 v = ((const float4*)W)[i];
        uint2 p;
        p.x = pack_bf16(v.x, v.y);
        p.y = pack_bf16(v.z, v.w);
        ((uint2*)WB)[i] = p;
    }
    if (i < NBUCK) bhist[i] = 0;
}

// ---------- bucket histogram: LDS hist per block, few global atomics ----------
__global__ __launch_bounds__(256) void bhist_kernel(const int* __restrict__ dst, int* __restrict__ bhist) {
    __shared__ int h[256];
    const int t = threadIdx.x;
    h[t] = 0;
    __syncthreads();
    for (int e = blockIdx.x * 256 + t; e < N_EDGES; e += gridDim.x * 256)
        atomicAdd(&h[dst[e] >> 8], 1);
    __syncthreads();
    if (t < NBUCK && h[t]) atomicAdd(&bhist[t], h[t]);
}

// ---------- scan bucket counts (1 block) ----------
__global__ __launch_bounds__(256) void bscan_kernel(const int* __restrict__ bhist, int* __restrict__ bbase,
                                                    int* __restrict__ bcur, int* __restrict__ off) {
    __shared__ int sh[256];
    const int t = threadIdx.x;
    const int v = (t < NBUCK) ? bhist[t] : 0;
    sh[t] = v;
    __syncthreads();
    for (int o = 1; o < 256; o <<= 1) {
        int x = (t >= o) ? sh[t - o] : 0;
        __syncthreads();
        sh[t] += x;
        __syncthreads();
    }
    const int excl = sh[t] - v;
    if (t < NBUCK) { bbase[t] = excl; bcur[t] = excl; }
    if (t == NBUCK - 1) bbase[NBUCK] = excl + v;   // == N_EDGES
    if (t == 0) off[N_NODES] = N_EDGES;
}

// ---------- partition edges into bucket regions (writes land in 32KB windows) ----------
__global__ __launch_bounds__(256) void part_kernel(const int* __restrict__ src, const int* __restrict__ dst,
                                                   int* __restrict__ bcur, int2* __restrict__ pak) {
    const int e = blockIdx.x * 256 + threadIdx.x;
    if (e < N_EDGES) {
        const int s = src[e], d = dst[e];
        const int p = atomicAdd(&bcur[d >> 8], 1);
        pak[p] = make_int2(s, d);
    }
}

// ---------- per-bucket CSR: count/scan/scatter in LDS; csr writes L2-local ----------
__global__ __launch_bounds__(256) void bucket_kernel(const int2* __restrict__ pak, const int* __restrict__ bbase,
                                                     int* __restrict__ off, int* __restrict__ csr) {
    __shared__ int cnt[256];
    __shared__ int pos[256];
    const int b = blockIdx.x, t = threadIdx.x;
    const int e0 = bbase[b], e1 = bbase[b + 1], m = e1 - e0;
    cnt[t] = 0;
    __syncthreads();
    for (int i = t; i < m; i += 256) atomicAdd(&cnt[pak[e0 + i].y & 255], 1);
    __syncthreads();
    const int v = cnt[t];
    pos[t] = v;
    __syncthreads();
    for (int o = 1; o < 256; o <<= 1) {
        int x = (t >= o) ? pos[t - o] : 0;
        __syncthreads();
        pos[t] += x;
        __syncthreads();
    }
    const int excl = pos[t] - v;
    const int node = b * 256 + t;
    if (node < N_NODES) off[node] = e0 + excl;
    __syncthreads();
    pos[t] = excl;                               // reuse as cursor
    __syncthreads();
    for (int i = t; i < m; i += 256) {
        const int2 p = pak[e0 + i];
        const int q = atomicAdd(&pos[p.y & 255], 1);
        csr[e0 + q] = p.x;                       // within bucket's 16KB window
    }
}

// ---------- aggregate: x_mean = (self + sum_neigh)/(deg+1), bf16 out ----------
// 16-lane stream per node, 16 nodes/block, 8 rows in flight (round-8 measured form).
// F32IN: read fp32 rows (layer 1, raw embedding); else bf16 rows.
template <bool F32IN>
__global__ __launch_bounds__(256) void agg_kernel(
    const void* __restrict__ finv, ushort* __restrict__ xout,
    const int* __restrict__ off, const int* __restrict__ csr,
    const int* __restrict__ uidmap)
{
    const int t    = threadIdx.x;
    const int lx   = t & 15;                     // covers elems lx*8 .. lx*8+7
    const int slot = blockIdx.x * 16 + (t >> 4);
    const int n    = uidmap ? uidmap[slot] : slot;
    const int d0   = off[n], d1 = off[n + 1];
    const int deg  = d1 - d0;

    float a[8];
    if constexpr (F32IN) {
        const float4* p = (const float4*)((const float*)finv + (size_t)n * DIM);
        const float4 u = p[2 * lx], w = p[2 * lx + 1];
        a[0]=u.x; a[1]=u.y; a[2]=u.z; a[3]=u.w; a[4]=w.x; a[5]=w.y; a[6]=w.z; a[7]=w.w;
    } else {
        const uint4 q = ((const uint4*)((const ushort*)finv + (size_t)n * DIM))[lx];
        a[0]=bf_lo(q.x); a[1]=bf_hi(q.x); a[2]=bf_lo(q.y); a[3]=bf_hi(q.y);
        a[4]=bf_lo(q.z); a[5]=bf_hi(q.z); a[6]=bf_lo(q.w); a[7]=bf_hi(q.w);
    }

    const int nfull = deg >> 3;
    int e = d0;
    int id[8];
    if (nfull > 0) {
        #pragma unroll
        for (int k = 0; k < 8; ++k) id[k] = csr[e + k];
    }
    for (int r = 0; r < nfull; ++r) {
        int idn[8];
        if constexpr (F32IN) {
            float4 u[8], w[8];
            #pragma unroll
            for (int k = 0; k < 8; ++k) {
                const float4* p = (const float4*)((const float*)finv + (size_t)id[k] * DIM);
                u[k] = p[2 * lx]; w[k] = p[2 * lx + 1];
            }
            if (r + 1 < nfull) {
                #pragma unroll
                for (int k = 0; k < 8; ++k) idn[k] = csr[e + 8 + k];
            }
            #pragma unroll
            for (int k = 0; k < 8; ++k) {
                a[0] += u[k].x; a[1] += u[k].y; a[2] += u[k].z; a[3] += u[k].w;
                a[4] += w[k].x; a[5] += w[k].y; a[6] += w[k].z; a[7] += w[k].w;
            }
        } else {
            uint4 v[8];
            #pragma unroll
            for (int k = 0; k < 8; ++k)
                v[k] = ((const uint4*)((const ushort*)finv + (size_t)id[k] * DIM))[lx];
            if (r + 1 < nfull) {
                #pragma unroll
                for (int k = 0; k < 8; ++k) idn[k] = csr[e + 8 + k];
            }
            #pragma unroll
            for (int k = 0; k < 8; ++k) {
                a[0] += bf_lo(v[k].x); a[1] += bf_hi(v[k].x);
                a[2] += bf_lo(v[k].y); a[3] += bf_hi(v[k].y);
                a[4] += bf_lo(v[k].z); a[5] += bf_hi(v[k].z);
                a[6] += bf_lo(v[k].w); a[7] += bf_hi(v[k].w);
            }
        }
        if (r + 1 < nfull) {
            #pragma unroll
            for (int k = 0; k < 8; ++k) id[k] = idn[k];
        }
        e += 8;
    }
    if (e < d1) {                                // one masked 8-wide tail round
        const int last = d1 - 1;
        int   idt[8];
        float m[8];
        #pragma unroll
        for (int k = 0; k < 8; ++k) {
            const int ee = e + k;
            idt[k] = csr[(ee <= last) ? ee : last];
            m[k]   = (ee <= last) ? 1.0f : 0.0f;
        }
        if constexpr (F32IN) {
            float4 u[8], w[8];
            #pragma unroll
            for (int k = 0; k < 8; ++k) {
                const float4* p = (const float4*)((const float*)finv + (size_t)idt[k] * DIM);
                u[k] = p[2 * lx]; w[k] = p[2 * lx + 1];
            }
            #pragma unroll
            for (int k = 0; k < 8; ++k) {
                a[0] = fmaf(m[k], u[k].x, a[0]); a[1] = fmaf(m[k], u[k].y, a[1]);
                a[2] = fmaf(m[k], u[k].z, a[2]); a[3] = fmaf(m[k], u[k].w, a[3]);
                a[4] = fmaf(m[k], w[k].x, a[4]); a[5] = fmaf(m[k], w[k].y, a[5]);
                a[6] = fmaf(m[k], w[k].z, a[6]); a[7] = fmaf(m[k], w[k].w, a[7]);
            }
        } else {
            uint4 v[8];
            #pragma unroll
            for (int k = 0; k < 8; ++k)
                v[k] = ((const uint4*)((const ushort*)finv + (size_t)idt[k] * DIM))[lx];
            #pragma unroll
            for (int k = 0; k < 8; ++k) {
                a[0] = fmaf(m[k], bf_lo(v[k].x), a[0]); a[1] = fmaf(m[k], bf_hi(v[k].x), a[1]);
                a[2] = fmaf(m[k], bf_lo(v[k].y), a[2]); a[3] = fmaf(m[k], bf_hi(v[k].y), a[3]);
                a[4] = fmaf(m[k], bf_lo(v[k].z), a[4]); a[5] = fmaf(m[k], bf_hi(v[k].z), a[5]);
                a[6] = fmaf(m[k], bf_lo(v[k].w), a[6]); a[7] = fmaf(m[k], bf_hi(v[k].w), a[7]);
            }
        }
    }

    const float iv = 1.0f / (float)(deg + 1);
    uint4 p;
    p.x = pack_bf16(a[0] * iv, a[1] * iv);
    p.y = pack_bf16(a[2] * iv, a[3] * iv);
    p.z = pack_bf16(a[4] * iv, a[5] * iv);
    p.w = pack_bf16(a[6] * iv, a[7] * iv);
    ((uint4*)(xout + (size_t)slot * DIM))[lx] = p;
}

// ---------- MFMA dense: y = x_mean @ W^T (+b), LN, ELU ----------
// block = 256 threads (4 waves), 32 rows × 128 cols of output.
// C/D: col = lane&15, row = (lane>>4)*4 + reg   [measured m89]
template <bool OUT_BF16>
__global__ __launch_bounds__(256) void mgemm_kernel(
    const ushort* __restrict__ xin, void* __restrict__ fout,
    const ushort* __restrict__ wb, const float* __restrict__ bias,
    const float* __restrict__ gamma, const float* __restrict__ beta, int nrows)
{
    __shared__ float ys[32 * RST];
    const int t    = threadIdx.x;
    const int wave = t >> 6, lane = t & 63;
    const int rows = blockIdx.x * 32;
    const int row_off = (wave >> 1) * 16;
    const int col_off = (wave & 1) * 64;
    const int lm   = lane & 15;
    const int quad = lane >> 4;

    f32x4 acc[4] = {f32x4{0,0,0,0}, f32x4{0,0,0,0}, f32x4{0,0,0,0}, f32x4{0,0,0,0}};
    const ushort* __restrict__ xrow = xin + (size_t)(rows + row_off + lm) * DIM + quad * 8;
    const ushort* __restrict__ wrow = wb  + (size_t)(col_off + lm) * DIM + quad * 8;
    #pragma unroll
    for (int kk = 0; kk < 4; ++kk) {
        const bf16x8 a = __builtin_bit_cast(bf16x8, *(const u32x4*)(xrow + kk * 32));
        #pragma unroll
        for (int c = 0; c < 4; ++c) {
            const bf16x8 b = __builtin_bit_cast(bf16x8,
                *(const u32x4*)(wrow + (size_t)c * 16 * DIM + kk * 32));
            acc[c] = __builtin_amdgcn_mfma_f32_16x16x32_bf16(a, b, acc[c], 0, 0, 0);
        }
    }

    #pragma unroll
    for (int c = 0; c < 4; ++c) {
        #pragma unroll
        for (int r = 0; r < 4; ++r)
            ys[(row_off + quad * 4 + r) * RST + col_off + c * 16 + lm] = acc[c][r];
    }
    __syncthreads();

    // LN + ELU: 8 threads per row, 16 dims each
    {
        const int r   = t >> 3;              // row 0..31
        const int seg = t & 7;               // 0..7
        const int db  = seg * 16;
        const float* yr = ys + r * RST + db;
        float vs[16];
        #pragma unroll
        for (int q = 0; q < 4; ++q) {
            const float4 y4 = ((const float4*)yr)[q];
            const float4 b4 = ((const float4*)(bias + db))[q];
            vs[q * 4 + 0] = y4.x + b4.x;
            vs[q * 4 + 1] = y4.y + b4.y;
            vs[q * 4 + 2] = y4.z + b4.z;
            vs[q * 4 + 3] = y4.w + b4.w;
        }
        float s1 = 0.0f, s2 = 0.0f;
        #pragma unroll
        for (int i = 0; i < 16; ++i) { s1 += vs[i]; s2 += vs[i] * vs[i]; }
        #pragma unroll
        for (int m = 1; m < 8; m <<= 1) {
            s1 += __shfl_xor(s1, m);
            s2 += __shfl_xor(s2, m);
        }
        const float mu  = s1 * (1.0f / 128.0f);
        const float var = s2 * (1.0f / 128.0f) - mu * mu;
        const float rs  = rsqrtf(var + LN_EPS);
        float ov[16];
        #pragma unroll
        for (int q = 0; q < 4; ++q) {
            const float4 g4 = ((const float4*)(gamma + db))[q];
            const float4 t4 = ((const float4*)(beta + db))[q];
            float z;
            z = (vs[q*4+0] - mu) * rs * g4.x + t4.x; ov[q*4+0] = (z > 0.0f) ? z : expm1f(z);
            z = (vs[q*4+1] - mu) * rs * g4.y + t4.y; ov[q*4+1] = (z > 0.0f) ? z : expm1f(z);
            z = (vs[q*4+2] - mu) * rs * g4.z + t4.z; ov[q*4+2] = (z > 0.0f) ? z : expm1f(z);
            z = (vs[q*4+3] - mu) * rs * g4.w + t4.w; ov[q*4+3] = (z > 0.0f) ? z : expm1f(z);
        }
        const int n = rows + r;
        if (n < nrows) {
            if (OUT_BF16) {
                uint4 p0, p1;
                p0.x = pack_bf16(ov[0],  ov[1]);  p0.y = pack_bf16(ov[2],  ov[3]);
                p0.z = pack_bf16(ov[4],  ov[5]);  p0.w = pack_bf16(ov[6],  ov[7]);
                p1.x = pack_bf16(ov[8],  ov[9]);  p1.y = pack_bf16(ov[10], ov[11]);
                p1.z = pack_bf16(ov[12], ov[13]); p1.w = pack_bf16(ov[14], ov[15]);
                uint4* op = (uint4*)((ushort*)fout + (size_t)n * DIM + db);
                op[0] = p0;
                op[1] = p1;
            } else {
                float* op = (float*)fout + (size_t)n * DIM + db;
                ((float4*)op)[0] = make_float4(ov[0],  ov[1],  ov[2],  ov[3]);
                ((float4*)op)[1] = make_float4(ov[4],  ov[5],  ov[6],  ov[7]);
                ((float4*)op)[2] = make_float4(ov[8],  ov[9],  ov[10], ov[11]);
                ((float4*)op)[3] = make_float4(ov[12], ov[13], ov[14], ov[15]);
            }
        }
    }
}

extern "C" void kernel_launch(void* const* d_in, const int* in_sizes, int n_in,
                              void* d_out, int out_size, void* d_ws, size_t ws_size,
                              hipStream_t stream) {
    const float* emb   = (const float*)d_in[0];
    const float* W     = (const float*)d_in[1];
    const float* bias  = (const float*)d_in[2];
    const float* gamma = (const float*)d_in[3];
    const float* beta  = (const float*)d_in[4];
    const int*   src   = (const int*)d_in[5];
    const int*   dst   = (const int*)d_in[6];
    const int*   uid   = (const int*)d_in[7];

    // workspace layout (~48 MB)
    ushort* X    = (ushort*)d_ws;                     // (50000+64)*128 bf16 (x_mean, padded)
    ushort* A    = X + (size_t)(N_NODES + 64) * DIM;  // 50000*128 bf16
    ushort* B    = A + (size_t)N_NODES * DIM;         // 50000*128 bf16
    ushort* WB   = B + (size_t)N_NODES * DIM;         // 3*128*128 bf16
    int*    off  = (int*)(WB + 3 * DIM * DIM);        // 50001 (+pad to 50004)
    int*    bhist = off + (N_NODES + 4);              // 256
    int*    bbase = bhist + 256;                      // 260 (NBUCK+1 +pad)
    int*    bcur  = bbase + 260;                      // 256
    int2*   pak   = (int2*)(bcur + 256);              // 800000 int2 (8B aligned)
    int*    csr   = (int*)(pak + N_EDGES);            // 800000

    const int eblk = (N_EDGES + 255) / 256;           // 3125
    prep_kernel<<<48, 256, 0, stream>>>(W, WB, bhist);
    bhist_kernel<<<512, 256, 0, stream>>>(dst, bhist);
    bscan_kernel<<<1, 256, 0, stream>>>(bhist, bbase, bcur, off);
    part_kernel<<<eblk, 256, 0, stream>>>(src, dst, bcur, pak);
    bucket_kernel<<<NBUCK, 256, 0, stream>>>(pak, bbase, off, csr);

    const int ablk = N_NODES / 16;                    // 3125
    const int gblk = (N_NODES + 31) / 32;             // 1563
    // layer 1 (reads raw fp32 embedding — no bf16 copy needed)
    agg_kernel<true><<<ablk, 256, 0, stream>>>(emb, X, off, csr, nullptr);
    mgemm_kernel<true><<<gblk, 256, 0, stream>>>(X, A, WB, bias, gamma, beta, N_NODES);
    // layer 2
    agg_kernel<false><<<ablk, 256, 0, stream>>>(A, X, off, csr, nullptr);
    mgemm_kernel<true><<<gblk, 256, 0, stream>>>(X, B, WB + DIM * DIM, bias + DIM,
                                                 gamma + DIM, beta + DIM, N_NODES);
    // layer 3: only uid nodes are read — aggregate + transform just those
    agg_kernel<false><<<N_UID / 16, 256, 0, stream>>>(B, X, off, csr, uid);
    mgemm_kernel<false><<<N_UID / 32, 256, 0, stream>>>(X, (float*)d_out, WB + 2 * DIM * DIM,
                                                        bias + 2 * DIM, gamma + 2 * DIM,
                                                        beta + 2 * DIM, N_UID);
}

// Round 11
// 271.908 us; speedup vs baseline: 2.5973x; 2.5973x over previous
//
#include <hip/hip_runtime.h>
#include <math.h>

typedef unsigned int   uint;
typedef unsigned short ushort;

#define N_NODES 50000
#define DIM     128
#define N_EDGES 800000
#define N_UID   4096
#define LN_EPS  1e-5f
#define RST     132   // padded LDS row stride (floats)
#define NBUCK   196   // ceil(50000/256) buckets of 256 nodes
#define PCHUNK  4096  // edges per part block

typedef __attribute__((ext_vector_type(8))) short bf16x8;
typedef __attribute__((ext_vector_type(4))) float f32x4;
typedef __attribute__((ext_vector_type(4))) uint  u32x4;

// ---- bf16 helpers (storage only; math fp32) ----
__device__ __forceinline__ float bf_lo(uint u) { return __builtin_bit_cast(float, u << 16); }
__device__ __forceinline__ float bf_hi(uint u) { return __builtin_bit_cast(float, u & 0xffff0000u); }
__device__ __forceinline__ uint pack_bf16(float a, float b) {   // RNE
    uint ua = __builtin_bit_cast(uint, a);
    uint ub = __builtin_bit_cast(uint, b);
    uint ra = (ua + 0x7fffu + ((ua >> 16) & 1u)) >> 16;
    uint rb = (ub + 0x7fffu + ((ub >> 16) & 1u)) >> 16;
    return ra | (rb << 16);
}

// ---------- prep: W -> bf16, zero bucket histogram ----------
__global__ __launch_bounds__(256) void prep_kernel(const float* __restrict__ W, ushort* __restrict__ WB,
                                                   int* __restrict__ bhist) {
    int i = blockIdx.x * 256 + threadIdx.x;
    if (i < 3 * DIM * DIM / 4) {
        const float4 v = ((const float4*)W)[i];
        uint2 p;
        p.x = pack_bf16(v.x, v.y);
        p.y = pack_bf16(v.z, v.w);
        ((uint2*)WB)[i] = p;
    }
    if (i < NBUCK) bhist[i] = 0;
}

// ---------- bucket histogram: LDS hist per block, few global atomics ----------
__global__ __launch_bounds__(256) void bhist_kernel(const int* __restrict__ dst, int* __restrict__ bhist) {
    __shared__ int h[256];
    const int t = threadIdx.x;
    h[t] = 0;
    __syncthreads();
    for (int e = blockIdx.x * 256 + t; e < N_EDGES; e += gridDim.x * 256)
        atomicAdd(&h[dst[e] >> 8], 1);
    __syncthreads();
    if (t < NBUCK && h[t]) atomicAdd(&bhist[t], h[t]);
}

// ---------- scan bucket counts (1 block) ----------
__global__ __launch_bounds__(256) void bscan_kernel(const int* __restrict__ bhist, int* __restrict__ bbase,
                                                    int* __restrict__ bcur, int* __restrict__ off) {
    __shared__ int sh[256];
    const int t = threadIdx.x;
    const int v = (t < NBUCK) ? bhist[t] : 0;
    sh[t] = v;
    __syncthreads();
    for (int o = 1; o < 256; o <<= 1) {
        int x = (t >= o) ? sh[t - o] : 0;
        __syncthreads();
        sh[t] += x;
        __syncthreads();
    }
    const int excl = sh[t] - v;
    if (t < NBUCK) { bbase[t] = excl; bcur[t] = excl; }
    if (t == NBUCK - 1) bbase[NBUCK] = excl + v;   // == N_EDGES
    if (t == 0) off[N_NODES] = N_EDGES;
}

// ---------- partition edges into bucket regions ----------
// Block-aggregated reservation: LDS histogram of the block's 4096-edge chunk,
// ONE global atomic per (block, nonempty bucket) to reserve a window, then
// LDS-cursor scatter. Global atomics: 800k -> ~38k spread over 196 addrs.
__global__ __launch_bounds__(256) void part_kernel(const int* __restrict__ src, const int* __restrict__ dst,
                                                   int* __restrict__ bcur, int2* __restrict__ pak) {
    __shared__ int h[256];
    __shared__ int base[256];
    __shared__ int cur[256];
    const int t  = threadIdx.x;
    const int e0 = blockIdx.x * PCHUNK;
    const int e1 = min(e0 + PCHUNK, N_EDGES);
    h[t] = 0;
    __syncthreads();
    for (int i = e0 + t; i < e1; i += 256)
        atomicAdd(&h[dst[i] >> 8], 1);
    __syncthreads();
    if (t < NBUCK && h[t]) base[t] = atomicAdd(&bcur[t], h[t]);
    cur[t] = 0;
    __syncthreads();
    for (int i = e0 + t; i < e1; i += 256) {
        const int s = src[i], d = dst[i];
        const int b = d >> 8;
        const int q = atomicAdd(&cur[b], 1);
        pak[base[b] + q] = make_int2(s, d);
    }
}

// ---------- per-bucket CSR: count/scan/scatter in LDS; csr writes L2-local ----------
__global__ __launch_bounds__(256) void bucket_kernel(const int2* __restrict__ pak, const int* __restrict__ bbase,
                                                     int* __restrict__ off, int* __restrict__ csr) {
    __shared__ int cnt[256];
    __shared__ int pos[256];
    const int b = blockIdx.x, t = threadIdx.x;
    const int e0 = bbase[b], e1 = bbase[b + 1], m = e1 - e0;
    cnt[t] = 0;
    __syncthreads();
    for (int i = t; i < m; i += 256) atomicAdd(&cnt[pak[e0 + i].y & 255], 1);
    __syncthreads();
    const int v = cnt[t];
    pos[t] = v;
    __syncthreads();
    for (int o = 1; o < 256; o <<= 1) {
        int x = (t >= o) ? pos[t - o] : 0;
        __syncthreads();
        pos[t] += x;
        __syncthreads();
    }
    const int excl = pos[t] - v;
    const int node = b * 256 + t;
    if (node < N_NODES) off[node] = e0 + excl;
    __syncthreads();
    pos[t] = excl;                               // reuse as cursor
    __syncthreads();
    for (int i = t; i < m; i += 256) {
        const int2 p = pak[e0 + i];
        const int q = atomicAdd(&pos[p.y & 255], 1);
        csr[e0 + q] = p.x;                       // within bucket's 16KB window
    }
}

// ---------- aggregate: x_mean = (self + sum_neigh)/(deg+1), bf16 out ----------
// 16-lane stream per node, 16 nodes/block, 8 rows in flight (round-8 measured form).
// F32IN: read fp32 rows (layer 1, raw embedding); else bf16 rows.
template <bool F32IN>
__global__ __launch_bounds__(256) void agg_kernel(
    const void* __restrict__ finv, ushort* __restrict__ xout,
    const int* __restrict__ off, const int* __restrict__ csr,
    const int* __restrict__ uidmap)
{
    const int t    = threadIdx.x;
    const int lx   = t & 15;                     // covers elems lx*8 .. lx*8+7
    const int slot = blockIdx.x * 16 + (t >> 4);
    const int n    = uidmap ? uidmap[slot] : slot;
    const int d0   = off[n], d1 = off[n + 1];
    const int deg  = d1 - d0;

    float a[8];
    if constexpr (F32IN) {
        const float4* p = (const float4*)((const float*)finv + (size_t)n * DIM);
        const float4 u = p[2 * lx], w = p[2 * lx + 1];
        a[0]=u.x; a[1]=u.y; a[2]=u.z; a[3]=u.w; a[4]=w.x; a[5]=w.y; a[6]=w.z; a[7]=w.w;
    } else {
        const uint4 q = ((const uint4*)((const ushort*)finv + (size_t)n * DIM))[lx];
        a[0]=bf_lo(q.x); a[1]=bf_hi(q.x); a[2]=bf_lo(q.y); a[3]=bf_hi(q.y);
        a[4]=bf_lo(q.z); a[5]=bf_hi(q.z); a[6]=bf_lo(q.w); a[7]=bf_hi(q.w);
    }

    const int nfull = deg >> 3;
    int e = d0;
    int id[8];
    if (nfull > 0) {
        #pragma unroll
        for (int k = 0; k < 8; ++k) id[k] = csr[e + k];
    }
    for (int r = 0; r < nfull; ++r) {
        int idn[8];
        if constexpr (F32IN) {
            float4 u[8], w[8];
            #pragma unroll
            for (int k = 0; k < 8; ++k) {
                const float4* p = (const float4*)((const float*)finv + (size_t)id[k] * DIM);
                u[k] = p[2 * lx]; w[k] = p[2 * lx + 1];
            }
            if (r + 1 < nfull) {
                #pragma unroll
                for (int k = 0; k < 8; ++k) idn[k] = csr[e + 8 + k];
            }
            #pragma unroll
            for (int k = 0; k < 8; ++k) {
                a[0] += u[k].x; a[1] += u[k].y; a[2] += u[k].z; a[3] += u[k].w;
                a[4] += w[k].x; a[5] += w[k].y; a[6] += w[k].z; a[7] += w[k].w;
            }
        } else {
            uint4 v[8];
            #pragma unroll
            for (int k = 0; k < 8; ++k)
                v[k] = ((const uint4*)((const ushort*)finv + (size_t)id[k] * DIM))[lx];
            if (r + 1 < nfull) {
                #pragma unroll
                for (int k = 0; k < 8; ++k) idn[k] = csr[e + 8 + k];
            }
            #pragma unroll
            for (int k = 0; k < 8; ++k) {
                a[0] += bf_lo(v[k].x); a[1] += bf_hi(v[k].x);
                a[2] += bf_lo(v[k].y); a[3] += bf_hi(v[k].y);
                a[4] += bf_lo(v[k].z); a[5] += bf_hi(v[k].z);
                a[6] += bf_lo(v[k].w); a[7] += bf_hi(v[k].w);
            }
        }
        if (r + 1 < nfull) {
            #pragma unroll
            for (int k = 0; k < 8; ++k) id[k] = idn[k];
        }
        e += 8;
    }
    if (e < d1) {                                // one masked 8-wide tail round
        const int last = d1 - 1;
        int   idt[8];
        float m[8];
        #pragma unroll
        for (int k = 0; k < 8; ++k) {
            const int ee = e + k;
            idt[k] = csr[(ee <= last) ? ee : last];
            m[k]   = (ee <= last) ? 1.0f : 0.0f;
        }
        if constexpr (F32IN) {
            float4 u[8], w[8];
            #pragma unroll
            for (int k = 0; k < 8; ++k) {
                const float4* p = (const float4*)((const float*)finv + (size_t)idt[k] * DIM);
                u[k] = p[2 * lx]; w[k] = p[2 * lx + 1];
            }
            #pragma unroll
            for (int k = 0; k < 8; ++k) {
                a[0] = fmaf(m[k], u[k].x, a[0]); a[1] = fmaf(m[k], u[k].y, a[1]);
                a[2] = fmaf(m[k], u[k].z, a[2]); a[3] = fmaf(m[k], u[k].w, a[3]);
                a[4] = fmaf(m[k], w[k].x, a[4]); a[5] = fmaf(m[k], w[k].y, a[5]);
                a[6] = fmaf(m[k], w[k].z, a[6]); a[7] = fmaf(m[k], w[k].w, a[7]);
            }
        } else {
            uint4 v[8];
            #pragma unroll
            for (int k = 0; k < 8; ++k)
                v[k] = ((const uint4*)((const ushort*)finv + (size_t)idt[k] * DIM))[lx];
            #pragma unroll
            for (int k = 0; k < 8; ++k) {
                a[0] = fmaf(m[k], bf_lo(v[k].x), a[0]); a[1] = fmaf(m[k], bf_hi(v[k].x), a[1]);
                a[2] = fmaf(m[k], bf_lo(v[k].y), a[2]); a[3] = fmaf(m[k], bf_hi(v[k].y), a[3]);
                a[4] = fmaf(m[k], bf_lo(v[k].z), a[4]); a[5] = fmaf(m[k], bf_hi(v[k].z), a[5]);
                a[6] = fmaf(m[k], bf_lo(v[k].w), a[6]); a[7] = fmaf(m[k], bf_hi(v[k].w), a[7]);
            }
        }
    }

    const float iv = 1.0f / (float)(deg + 1);
    uint4 p;
    p.x = pack_bf16(a[0] * iv, a[1] * iv);
    p.y = pack_bf16(a[2] * iv, a[3] * iv);
    p.z = pack_bf16(a[4] * iv, a[5] * iv);
    p.w = pack_bf16(a[6] * iv, a[7] * iv);
    ((uint4*)(xout + (size_t)slot * DIM))[lx] = p;
}

// ---------- MFMA dense: y = x_mean @ W^T (+b), LN, ELU ----------
// block = 256 threads (4 waves), 32 rows × 128 cols of output.
// C/D: col = lane&15, row = (lane>>4)*4 + reg   [measured m89]
template <bool OUT_BF16>
__global__ __launch_bounds__(256) void mgemm_kernel(
    const ushort* __restrict__ xin, void* __restrict__ fout,
    const ushort* __restrict__ wb, const float* __restrict__ bias,
    const float* __restrict__ gamma, const float* __restrict__ beta, int nrows)
{
    __shared__ float ys[32 * RST];
    const int t    = threadIdx.x;
    const int wave = t >> 6, lane = t & 63;
    const int rows = blockIdx.x * 32;
    const int row_off = (wave >> 1) * 16;
    const int col_off = (wave & 1) * 64;
    const int lm   = lane & 15;
    const int quad = lane >> 4;

    f32x4 acc[4] = {f32x4{0,0,0,0}, f32x4{0,0,0,0}, f32x4{0,0,0,0}, f32x4{0,0,0,0}};
    const ushort* __restrict__ xrow = xin + (size_t)(rows + row_off + lm) * DIM + quad * 8;
    const ushort* __restrict__ wrow = wb  + (size_t)(col_off + lm) * DIM + quad * 8;
    #pragma unroll
    for (int kk = 0; kk < 4; ++kk) {
        const bf16x8 a = __builtin_bit_cast(bf16x8, *(const u32x4*)(xrow + kk * 32));
        #pragma unroll
        for (int c = 0; c < 4; ++c) {
            const bf16x8 b = __builtin_bit_cast(bf16x8,
                *(const u32x4*)(wrow + (size_t)c * 16 * DIM + kk * 32));
            acc[c] = __builtin_amdgcn_mfma_f32_16x16x32_bf16(a, b, acc[c], 0, 0, 0);
        }
    }

    #pragma unroll
    for (int c = 0; c < 4; ++c) {
        #pragma unroll
        for (int r = 0; r < 4; ++r)
            ys[(row_off + quad * 4 + r) * RST + col_off + c * 16 + lm] = acc[c][r];
    }
    __syncthreads();

    // LN + ELU: 8 threads per row, 16 dims each
    {
        const int r   = t >> 3;              // row 0..31
        const int seg = t & 7;               // 0..7
        const int db  = seg * 16;
        const float* yr = ys + r * RST + db;
        float vs[16];
        #pragma unroll
        for (int q = 0; q < 4; ++q) {
            const float4 y4 = ((const float4*)yr)[q];
            const float4 b4 = ((const float4*)(bias + db))[q];
            vs[q * 4 + 0] = y4.x + b4.x;
            vs[q * 4 + 1] = y4.y + b4.y;
            vs[q * 4 + 2] = y4.z + b4.z;
            vs[q * 4 + 3] = y4.w + b4.w;
        }
        float s1 = 0.0f, s2 = 0.0f;
        #pragma unroll
        for (int i = 0; i < 16; ++i) { s1 += vs[i]; s2 += vs[i] * vs[i]; }
        #pragma unroll
        for (int m = 1; m < 8; m <<= 1) {
            s1 += __shfl_xor(s1, m);
            s2 += __shfl_xor(s2, m);
        }
        const float mu  = s1 * (1.0f / 128.0f);
        const float var = s2 * (1.0f / 128.0f) - mu * mu;
        const float rs  = rsqrtf(var + LN_EPS);
        float ov[16];
        #pragma unroll
        for (int q = 0; q < 4; ++q) {
            const float4 g4 = ((const float4*)(gamma + db))[q];
            const float4 t4 = ((const float4*)(beta + db))[q];
            float z;
            z = (vs[q*4+0] - mu) * rs * g4.x + t4.x; ov[q*4+0] = (z > 0.0f) ? z : expm1f(z);
            z = (vs[q*4+1] - mu) * rs * g4.y + t4.y; ov[q*4+1] = (z > 0.0f) ? z : expm1f(z);
            z = (vs[q*4+2] - mu) * rs * g4.z + t4.z; ov[q*4+2] = (z > 0.0f) ? z : expm1f(z);
            z = (vs[q*4+3] - mu) * rs * g4.w + t4.w; ov[q*4+3] = (z > 0.0f) ? z : expm1f(z);
        }
        const int n = rows + r;
        if (n < nrows) {
            if (OUT_BF16) {
                uint4 p0, p1;
                p0.x = pack_bf16(ov[0],  ov[1]);  p0.y = pack_bf16(ov[2],  ov[3]);
                p0.z = pack_bf16(ov[4],  ov[5]);  p0.w = pack_bf16(ov[6],  ov[7]);
                p1.x = pack_bf16(ov[8],  ov[9]);  p1.y = pack_bf16(ov[10], ov[11]);
                p1.z = pack_bf16(ov[12], ov[13]); p1.w = pack_bf16(ov[14], ov[15]);
                uint4* op = (uint4*)((ushort*)fout + (size_t)n * DIM + db);
                op[0] = p0;
                op[1] = p1;
            } else {
                float* op = (float*)fout + (size_t)n * DIM + db;
                ((float4*)op)[0] = make_float4(ov[0],  ov[1],  ov[2],  ov[3]);
                ((float4*)op)[1] = make_float4(ov[4],  ov[5],  ov[6],  ov[7]);
                ((float4*)op)[2] = make_float4(ov[8],  ov[9],  ov[10], ov[11]);
                ((float4*)op)[3] = make_float4(ov[12], ov[13], ov[14], ov[15]);
            }
        }
    }
}

extern "C" void kernel_launch(void* const* d_in, const int* in_sizes, int n_in,
                              void* d_out, int out_size, void* d_ws, size_t ws_size,
                              hipStream_t stream) {
    const float* emb   = (const float*)d_in[0];
    const float* W     = (const float*)d_in[1];
    const float* bias  = (const float*)d_in[2];
    const float* gamma = (const float*)d_in[3];
    const float* beta  = (const float*)d_in[4];
    const int*   src   = (const int*)d_in[5];
    const int*   dst   = (const int*)d_in[6];
    const int*   uid   = (const int*)d_in[7];

    // workspace layout (~48 MB)
    ushort* X    = (ushort*)d_ws;                     // (50000+64)*128 bf16 (x_mean, padded)
    ushort* A    = X + (size_t)(N_NODES + 64) * DIM;  // 50000*128 bf16
    ushort* B    = A + (size_t)N_NODES * DIM;         // 50000*128 bf16
    ushort* WB   = B + (size_t)N_NODES * DIM;         // 3*128*128 bf16
    int*    off  = (int*)(WB + 3 * DIM * DIM);        // 50001 (+pad to 50004)
    int*    bhist = off + (N_NODES + 4);              // 256
    int*    bbase = bhist + 256;                      // 260 (NBUCK+1 +pad)
    int*    bcur  = bbase + 260;                      // 256
    int2*   pak   = (int2*)(bcur + 256);              // 800000 int2 (8B aligned)
    int*    csr   = (int*)(pak + N_EDGES);            // 800000

    prep_kernel<<<48, 256, 0, stream>>>(W, WB, bhist);
    bhist_kernel<<<512, 256, 0, stream>>>(dst, bhist);
    bscan_kernel<<<1, 256, 0, stream>>>(bhist, bbase, bcur, off);
    part_kernel<<<(N_EDGES + PCHUNK - 1) / PCHUNK, 256, 0, stream>>>(src, dst, bcur, pak);
    bucket_kernel<<<NBUCK, 256, 0, stream>>>(pak, bbase, off, csr);

    const int ablk = N_NODES / 16;                    // 3125
    const int gblk = (N_NODES + 31) / 32;             // 1563
    // layer 1 (reads raw fp32 embedding — no bf16 copy needed)
    agg_kernel<true><<<ablk, 256, 0, stream>>>(emb, X, off, csr, nullptr);
    mgemm_kernel<true><<<gblk, 256, 0, stream>>>(X, A, WB, bias, gamma, beta, N_NODES);
    // layer 2
    agg_kernel<false><<<ablk, 256, 0, stream>>>(A, X, off, csr, nullptr);
    mgemm_kernel<true><<<gblk, 256, 0, stream>>>(X, B, WB + DIM * DIM, bias + DIM,
                                                 gamma + DIM, beta + DIM, N_NODES);
    // layer 3: only uid nodes are read — aggregate + transform just those
    agg_kernel<false><<<N_UID / 16, 256, 0, stream>>>(B, X, off, csr, uid);
    mgemm_kernel<false><<<N_UID / 32, 256, 0, stream>>>(X, (float*)d_out, WB + 2 * DIM * DIM,
                                                        bias + 2 * DIM, gamma + 2 * DIM,
                                                        beta + 2 * DIM, N_UID);
}

// Round 12
// 230.472 us; speedup vs baseline: 3.0643x; 1.1798x over previous
//
#include <hip/hip_runtime.h>
#include <math.h>

typedef unsigned int   uint;
typedef unsigned short ushort;

#define N_NODES 50000
#define DIM     128
#define N_EDGES 800000
#define N_UID   4096
#define LN_EPS  1e-5f
#define RST     132   // padded LDS row stride for fp32 y (132*4 B)
#define XST     136   // padded LDS row stride for bf16 x (136*2=272 B -> 2-way bank alias, free)
#define NBUCK   196   // ceil(50000/256) buckets of 256 nodes
#define PCHUNK  4096  // edges per part block

typedef __attribute__((ext_vector_type(8))) short bf16x8;
typedef __attribute__((ext_vector_type(4))) float f32x4;
typedef __attribute__((ext_vector_type(4))) uint  u32x4;

// ---- bf16 helpers (storage only; math fp32) ----
__device__ __forceinline__ float bf_lo(uint u) { return __builtin_bit_cast(float, u << 16); }
__device__ __forceinline__ float bf_hi(uint u) { return __builtin_bit_cast(float, u & 0xffff0000u); }
__device__ __forceinline__ uint pack_bf16(float a, float b) {   // RNE
    uint ua = __builtin_bit_cast(uint, a);
    uint ub = __builtin_bit_cast(uint, b);
    uint ra = (ua + 0x7fffu + ((ua >> 16) & 1u)) >> 16;
    uint rb = (ub + 0x7fffu + ((ub >> 16) & 1u)) >> 16;
    return ra | (rb << 16);
}

// ---------- prep: emb -> bf16, W -> bf16, zero bucket histogram ----------
__global__ __launch_bounds__(256) void prep_kernel(const float* __restrict__ emb, ushort* __restrict__ E,
                                                   const float* __restrict__ W, ushort* __restrict__ WB,
                                                   int* __restrict__ bhist) {
    int i = blockIdx.x * 256 + threadIdx.x;
    if (i < N_NODES * DIM / 4) {
        const float4 v = ((const float4*)emb)[i];
        uint2 p;
        p.x = pack_bf16(v.x, v.y);
        p.y = pack_bf16(v.z, v.w);
        ((uint2*)E)[i] = p;
    }
    if (i < 3 * DIM * DIM / 4) {
        const float4 v = ((const float4*)W)[i];
        uint2 p;
        p.x = pack_bf16(v.x, v.y);
        p.y = pack_bf16(v.z, v.w);
        ((uint2*)WB)[i] = p;
    }
    if (i < NBUCK) bhist[i] = 0;
}

// ---------- bucket histogram: LDS hist per block, few global atomics ----------
__global__ __launch_bounds__(256) void bhist_kernel(const int* __restrict__ dst, int* __restrict__ bhist) {
    __shared__ int h[256];
    const int t = threadIdx.x;
    h[t] = 0;
    __syncthreads();
    for (int e = blockIdx.x * 256 + t; e < N_EDGES; e += gridDim.x * 256)
        atomicAdd(&h[dst[e] >> 8], 1);
    __syncthreads();
    if (t < NBUCK && h[t]) atomicAdd(&bhist[t], h[t]);
}

// ---------- scan bucket counts (1 block) ----------
__global__ __launch_bounds__(256) void bscan_kernel(const int* __restrict__ bhist, int* __restrict__ bbase,
                                                    int* __restrict__ bcur, int* __restrict__ off) {
    __shared__ int sh[256];
    const int t = threadIdx.x;
    const int v = (t < NBUCK) ? bhist[t] : 0;
    sh[t] = v;
    __syncthreads();
    for (int o = 1; o < 256; o <<= 1) {
        int x = (t >= o) ? sh[t - o] : 0;
        __syncthreads();
        sh[t] += x;
        __syncthreads();
    }
    const int excl = sh[t] - v;
    if (t < NBUCK) { bbase[t] = excl; bcur[t] = excl; }
    if (t == NBUCK - 1) bbase[NBUCK] = excl + v;   // == N_EDGES
    if (t == 0) off[N_NODES] = N_EDGES;
}

// ---------- partition: block-aggregated reservation (one atomic per block-bucket) ----------
__global__ __launch_bounds__(256) void part_kernel(const int* __restrict__ src, const int* __restrict__ dst,
                                                   int* __restrict__ bcur, int2* __restrict__ pak) {
    __shared__ int h[256];
    __shared__ int base[256];
    __shared__ int cur[256];
    const int t  = threadIdx.x;
    const int e0 = blockIdx.x * PCHUNK;
    const int e1 = min(e0 + PCHUNK, N_EDGES);
    h[t] = 0;
    __syncthreads();
    for (int i = e0 + t; i < e1; i += 256)
        atomicAdd(&h[dst[i] >> 8], 1);
    __syncthreads();
    if (t < NBUCK && h[t]) base[t] = atomicAdd(&bcur[t], h[t]);
    cur[t] = 0;
    __syncthreads();
    for (int i = e0 + t; i < e1; i += 256) {
        const int s = src[i], d = dst[i];
        const int b = d >> 8;
        const int q = atomicAdd(&cur[b], 1);
        pak[base[b] + q] = make_int2(s, d);
    }
}

// ---------- per-bucket CSR: count/scan/scatter in LDS; csr writes L2-local ----------
__global__ __launch_bounds__(256) void bucket_kernel(const int2* __restrict__ pak, const int* __restrict__ bbase,
                                                     int* __restrict__ off, int* __restrict__ csr) {
    __shared__ int cnt[256];
    __shared__ int pos[256];
    const int b = blockIdx.x, t = threadIdx.x;
    const int e0 = bbase[b], e1 = bbase[b + 1], m = e1 - e0;
    cnt[t] = 0;
    __syncthreads();
    for (int i = t; i < m; i += 256) atomicAdd(&cnt[pak[e0 + i].y & 255], 1);
    __syncthreads();
    const int v = cnt[t];
    pos[t] = v;
    __syncthreads();
    for (int o = 1; o < 256; o <<= 1) {
        int x = (t >= o) ? pos[t - o] : 0;
        __syncthreads();
        pos[t] += x;
        __syncthreads();
    }
    const int excl = pos[t] - v;
    const int node = b * 256 + t;
    if (node < N_NODES) off[node] = e0 + excl;
    __syncthreads();
    pos[t] = excl;                               // reuse as cursor
    __syncthreads();
    for (int i = t; i < m; i += 256) {
        const int2 p = pak[e0 + i];
        const int q = atomicAdd(&pos[p.y & 255], 1);
        csr[e0 + q] = p.x;                       // within bucket's 16KB window
    }
}

// ---------- fused layer: agg (barrier-free phase) + MFMA GEMM + LN + ELU ----------
// 512 threads, 32 nodes/block. Agg: one 16-lane stream per node, 8 rows in
// flight, x_mean packed bf16 into LDS (stride XST). One barrier. Then 8 waves:
// wave w: rows (w>>2)*16, cols (w&3)*32 (2 col-tiles of 16).
// C/D: col = lane&15, row = (lane>>4)*4 + reg   [measured m89]
template <bool OUT_BF16>
__global__ __launch_bounds__(512) void layer_kernel(
    const ushort* __restrict__ fin, void* __restrict__ fout,
    const int* __restrict__ off, const int* __restrict__ csr,
    const int* __restrict__ uidmap, const ushort* __restrict__ wb,
    const float* __restrict__ bias, const float* __restrict__ gamma,
    const float* __restrict__ beta, int nrows)
{
    __shared__ ushort xs[32 * XST];   // 8704 B  (bf16 x_mean)
    __shared__ float  ys[32 * RST];   // 16896 B (fp32 y)
    const int t = threadIdx.x;
    const int rows = blockIdx.x * 32;

    // ---- phase 1: aggregate (barrier-free, 8 rows in flight) ----
    {
        const int lx   = t & 15;                 // covers elems lx*8 .. lx*8+7
        const int st   = t >> 4;                 // node slot 0..31
        const int slot = rows + st;
        const bool valid = slot < nrows;
        const int n  = valid ? (uidmap ? uidmap[slot] : slot) : 0;
        const int d0 = off[n];
        int d1 = off[n + 1];
        if (!valid) d1 = d0;
        const int deg = d1 - d0;

        float a[8];
        {
            const uint4 q = ((const uint4*)(fin + (size_t)n * DIM))[lx];
            a[0]=bf_lo(q.x); a[1]=bf_hi(q.x); a[2]=bf_lo(q.y); a[3]=bf_hi(q.y);
            a[4]=bf_lo(q.z); a[5]=bf_hi(q.z); a[6]=bf_lo(q.w); a[7]=bf_hi(q.w);
        }

        const int nfull = deg >> 3;
        int e = d0;
        int id[8];
        if (nfull > 0) {
            #pragma unroll
            for (int k = 0; k < 8; ++k) id[k] = csr[e + k];
        }
        for (int r = 0; r < nfull; ++r) {
            uint4 v[8];
            #pragma unroll
            for (int k = 0; k < 8; ++k)
                v[k] = ((const uint4*)(fin + (size_t)id[k] * DIM))[lx];
            int idn[8];
            if (r + 1 < nfull) {                 // prefetch next round's indices
                #pragma unroll
                for (int k = 0; k < 8; ++k) idn[k] = csr[e + 8 + k];
            }
            #pragma unroll
            for (int k = 0; k < 8; ++k) {
                a[0] += bf_lo(v[k].x); a[1] += bf_hi(v[k].x);
                a[2] += bf_lo(v[k].y); a[3] += bf_hi(v[k].y);
                a[4] += bf_lo(v[k].z); a[5] += bf_hi(v[k].z);
                a[6] += bf_lo(v[k].w); a[7] += bf_hi(v[k].w);
            }
            if (r + 1 < nfull) {
                #pragma unroll
                for (int k = 0; k < 8; ++k) id[k] = idn[k];
            }
            e += 8;
        }
        if (e < d1) {                            // one masked 8-wide tail round
            const int last = d1 - 1;
            int   idt[8];
            float m[8];
            #pragma unroll
            for (int k = 0; k < 8; ++k) {
                const int ee = e + k;
                idt[k] = csr[(ee <= last) ? ee : last];
                m[k]   = (ee <= last) ? 1.0f : 0.0f;
            }
            uint4 v[8];
            #pragma unroll
            for (int k = 0; k < 8; ++k)
                v[k] = ((const uint4*)(fin + (size_t)idt[k] * DIM))[lx];
            #pragma unroll
            for (int k = 0; k < 8; ++k) {
                a[0] = fmaf(m[k], bf_lo(v[k].x), a[0]); a[1] = fmaf(m[k], bf_hi(v[k].x), a[1]);
                a[2] = fmaf(m[k], bf_lo(v[k].y), a[2]); a[3] = fmaf(m[k], bf_hi(v[k].y), a[3]);
                a[4] = fmaf(m[k], bf_lo(v[k].z), a[4]); a[5] = fmaf(m[k], bf_hi(v[k].z), a[5]);
                a[6] = fmaf(m[k], bf_lo(v[k].w), a[6]); a[7] = fmaf(m[k], bf_hi(v[k].w), a[7]);
            }
        }

        const float iv = 1.0f / (float)(deg + 1);
        uint4 p;
        p.x = pack_bf16(a[0] * iv, a[1] * iv);
        p.y = pack_bf16(a[2] * iv, a[3] * iv);
        p.z = pack_bf16(a[4] * iv, a[5] * iv);
        p.w = pack_bf16(a[6] * iv, a[7] * iv);
        *((uint4*)(xs + st * XST + lx * 8)) = p;
    }
    __syncthreads();

    // ---- phase 2: MFMA y = x @ W^T; 8 waves, rows 2x16, cols 4x32 ----
    {
        const int wave = t >> 6, lane = t & 63;
        const int row_off = (wave >> 2) * 16;
        const int col_off = (wave & 3) * 32;
        const int lm   = lane & 15;
        const int quad = lane >> 4;
        f32x4 acc[2] = {f32x4{0,0,0,0}, f32x4{0,0,0,0}};
        const ushort* xrow = xs + (row_off + lm) * XST + quad * 8;   // LDS
        const ushort* __restrict__ wrow = wb + (size_t)(col_off + lm) * DIM + quad * 8;
        #pragma unroll
        for (int kk = 0; kk < 4; ++kk) {
            const bf16x8 af = __builtin_bit_cast(bf16x8, *(const u32x4*)(xrow + kk * 32));
            #pragma unroll
            for (int c = 0; c < 2; ++c) {
                const bf16x8 bf = __builtin_bit_cast(bf16x8,
                    *(const u32x4*)(wrow + (size_t)c * 16 * DIM + kk * 32));
                acc[c] = __builtin_amdgcn_mfma_f32_16x16x32_bf16(af, bf, acc[c], 0, 0, 0);
            }
        }
        #pragma unroll
        for (int c = 0; c < 2; ++c) {
            #pragma unroll
            for (int r = 0; r < 4; ++r)
                ys[(row_off + quad * 4 + r) * RST + col_off + c * 16 + lm] = acc[c][r];
        }
    }
    __syncthreads();

    // ---- phase 3: LN + ELU; 16 threads per row, 8 dims each ----
    {
        const int r   = t >> 4;              // row 0..31
        const int seg = t & 15;              // 0..15
        const int db  = seg * 8;
        const float* yr = ys + r * RST + db;
        float vs[8];
        {
            const float4 y0 = ((const float4*)yr)[0];
            const float4 y1 = ((const float4*)yr)[1];
            const float4 b0 = ((const float4*)(bias + db))[0];
            const float4 b1 = ((const float4*)(bias + db))[1];
            vs[0] = y0.x + b0.x; vs[1] = y0.y + b0.y; vs[2] = y0.z + b0.z; vs[3] = y0.w + b0.w;
            vs[4] = y1.x + b1.x; vs[5] = y1.y + b1.y; vs[6] = y1.z + b1.z; vs[7] = y1.w + b1.w;
        }
        float s1 = 0.0f, s2 = 0.0f;
        #pragma unroll
        for (int i = 0; i < 8; ++i) { s1 += vs[i]; s2 += vs[i] * vs[i]; }
        #pragma unroll
        for (int m = 1; m < 16; m <<= 1) {
            s1 += __shfl_xor(s1, m);
            s2 += __shfl_xor(s2, m);
        }
        const float mu  = s1 * (1.0f / 128.0f);
        const float var = s2 * (1.0f / 128.0f) - mu * mu;
        const float rs  = rsqrtf(var + LN_EPS);
        float ov[8];
        {
            const float4 g0 = ((const float4*)(gamma + db))[0];
            const float4 g1 = ((const float4*)(gamma + db))[1];
            const float4 t0 = ((const float4*)(beta + db))[0];
            const float4 t1 = ((const float4*)(beta + db))[1];
            float z;
            z = (vs[0] - mu) * rs * g0.x + t0.x; ov[0] = (z > 0.0f) ? z : expm1f(z);
            z = (vs[1] - mu) * rs * g0.y + t0.y; ov[1] = (z > 0.0f) ? z : expm1f(z);
            z = (vs[2] - mu) * rs * g0.z + t0.z; ov[2] = (z > 0.0f) ? z : expm1f(z);
            z = (vs[3] - mu) * rs * g0.w + t0.w; ov[3] = (z > 0.0f) ? z : expm1f(z);
            z = (vs[4] - mu) * rs * g1.x + t1.x; ov[4] = (z > 0.0f) ? z : expm1f(z);
            z = (vs[5] - mu) * rs * g1.y + t1.y; ov[5] = (z > 0.0f) ? z : expm1f(z);
            z = (vs[6] - mu) * rs * g1.z + t1.z; ov[6] = (z > 0.0f) ? z : expm1f(z);
            z = (vs[7] - mu) * rs * g1.w + t1.w; ov[7] = (z > 0.0f) ? z : expm1f(z);
        }
        const int n = rows + r;
        if (n < nrows) {
            if (OUT_BF16) {
                uint4 p;
                p.x = pack_bf16(ov[0], ov[1]);
                p.y = pack_bf16(ov[2], ov[3]);
                p.z = pack_bf16(ov[4], ov[5]);
                p.w = pack_bf16(ov[6], ov[7]);
                *((uint4*)((ushort*)fout + (size_t)n * DIM + db)) = p;
            } else {
                float* op = (float*)fout + (size_t)n * DIM + db;
                ((float4*)op)[0] = make_float4(ov[0], ov[1], ov[2], ov[3]);
                ((float4*)op)[1] = make_float4(ov[4], ov[5], ov[6], ov[7]);
            }
        }
    }
}

extern "C" void kernel_launch(void* const* d_in, const int* in_sizes, int n_in,
                              void* d_out, int out_size, void* d_ws, size_t ws_size,
                              hipStream_t stream) {
    const float* emb   = (const float*)d_in[0];
    const float* W     = (const float*)d_in[1];
    const float* bias  = (const float*)d_in[2];
    const float* gamma = (const float*)d_in[3];
    const float* beta  = (const float*)d_in[4];
    const int*   src   = (const int*)d_in[5];
    const int*   dst   = (const int*)d_in[6];
    const int*   uid   = (const int*)d_in[7];

    // workspace layout (~46 MB)
    ushort* E    = (ushort*)d_ws;                     // 50000*128 bf16 (embedding)
    ushort* A    = E + (size_t)N_NODES * DIM;         // 50000*128 bf16
    ushort* B    = A + (size_t)N_NODES * DIM;         // 50000*128 bf16
    ushort* WB   = B + (size_t)N_NODES * DIM;         // 3*128*128 bf16
    int*    off  = (int*)(WB + 3 * DIM * DIM);        // 50001 (+pad to 50004)
    int*    bhist = off + (N_NODES + 4);              // 256
    int*    bbase = bhist + 256;                      // 260 (NBUCK+1 +pad)
    int*    bcur  = bbase + 260;                      // 256
    int2*   pak   = (int2*)(bcur + 256);              // 800000 int2 (8B aligned)
    int*    csr   = (int*)(pak + N_EDGES);            // 800000

    prep_kernel<<<(N_NODES * DIM / 4 + 255) / 256, 256, 0, stream>>>(emb, E, W, WB, bhist);
    bhist_kernel<<<512, 256, 0, stream>>>(dst, bhist);
    bscan_kernel<<<1, 256, 0, stream>>>(bhist, bbase, bcur, off);
    part_kernel<<<(N_EDGES + PCHUNK - 1) / PCHUNK, 256, 0, stream>>>(src, dst, bcur, pak);
    bucket_kernel<<<NBUCK, 256, 0, stream>>>(pak, bbase, off, csr);

    const int lblk = (N_NODES + 31) / 32;             // 1563
    layer_kernel<true><<<lblk, 512, 0, stream>>>(E, A, off, csr, nullptr, WB,
                                                 bias, gamma, beta, N_NODES);
    layer_kernel<true><<<lblk, 512, 0, stream>>>(A, B, off, csr, nullptr, WB + DIM * DIM,
                                                 bias + DIM, gamma + DIM, beta + DIM, N_NODES);
    // layer 3: only uid nodes are read — aggregate + transform just those, fp32 into d_out
    layer_kernel<false><<<N_UID / 32, 512, 0, stream>>>(B, (float*)d_out, off, csr, uid,
                                                        WB + 2 * DIM * DIM, bias + 2 * DIM,
                                                        gamma + 2 * DIM, beta + 2 * DIM, N_UID);
}